// Round 5
// baseline (202.455 us; speedup 1.0000x reference)
//
#include <hip/hip_runtime.h>

#define CNT   2048
#define TPB   256
#define RPB   4        // rows per block = waves per block (one wave per row)
#define NMAC  4        // macro-chunks per lane
#define MAC   8        // steps per macro-chunk; 4*8 = 32 steps/lane, 64 lanes = 2048

struct Q { float w, x, y, z; };

// full quaternion product: 16 fma-class ops, 3-deep chains
__device__ __forceinline__ Q qmul(const Q a, const Q b) {
    Q o;
    o.w = fmaf(a.w, b.w, fmaf(-a.x, b.x, fmaf(-a.y, b.y, -a.z * b.z)));
    o.x = fmaf(a.w, b.x, fmaf( a.x, b.w, fmaf( a.y, b.z, -a.z * b.y)));
    o.y = fmaf(a.w, b.y, fmaf(-a.x, b.z, fmaf( a.y, b.w,  a.z * b.x)));
    o.z = fmaf(a.w, b.z, fmaf( a.x, b.y, fmaf(-a.y, b.x,  a.z * b.w)));
    return o;
}

// qmul specialized for b.w == 1: 12 fma, 3-deep chains
__device__ __forceinline__ Q qmul1(const Q a, const float bx, const float by, const float bz) {
    Q o;
    o.w = fmaf(-a.x, bx, fmaf(-a.y, by, fmaf(-a.z, bz, a.w)));
    o.x = fmaf( a.w, bx, fmaf( a.y, bz, fmaf(-a.z, by, a.x)));
    o.y = fmaf( a.w, by, fmaf(-a.x, bz, fmaf( a.z, bx, a.y)));
    o.z = fmaf( a.w, bz, fmaf( a.x, by, fmaf(-a.y, bx, a.z)));
    return o;
}

// exact PReLU: a*x + (1-a)*relu(x) -> mul + max + fma
__device__ __forceinline__ float prelu(const float x, const float a, const float one_m_a) {
    return fmaf(one_m_a, fmaxf(x, 0.0f), a * x);
}

__global__ __launch_bounds__(TPB) void quat_scan_kernel(
    const float* __restrict__ ts,    // (B, CNT)
    const float* __restrict__ gyro,  // (B, CNT, 3)
    const float* __restrict__ sq,    // (B, 4)
    const float* __restrict__ W1, const float* __restrict__ b1, const float* __restrict__ a1p,
    const float* __restrict__ W2, const float* __restrict__ b2, const float* __restrict__ a2p,
    float* __restrict__ out,         // (B, 4)
    const int B)
{
    const int lane = threadIdx.x & 63;
    const int wid  = threadIdx.x >> 6;
    const int row  = blockIdx.x * RPB + wid;
    if (row >= B) return;            // wave-uniform exit, no divergence within a wave

    // ---- small params: wave-uniform scalar loads -> SGPRs
    float w1[9], w2[9], bb1[3], bb2[3];
    #pragma unroll
    for (int i = 0; i < 9; ++i) { w1[i] = W1[i]; w2[i] = W2[i]; }
    #pragma unroll
    for (int i = 0; i < 3; ++i) { bb1[i] = b1[i]; bb2[i] = b2[i]; }
    const float a1 = a1p[0], a2 = a2p[0];
    const float oma1 = 1.0f - a1, oma2 = 1.0f - a2;

    // g(v) = prelu(W2 @ prelu(W1 @ v + b1, a1) + b2, a2) + v
    auto gfv = [&](const float vx, const float vy, const float vz,
                   float& gx, float& gy, float& gz) {
        float h0 = fmaf(w1[0], vx, fmaf(w1[1], vy, fmaf(w1[2], vz, bb1[0])));
        float h1 = fmaf(w1[3], vx, fmaf(w1[4], vy, fmaf(w1[5], vz, bb1[1])));
        float h2 = fmaf(w1[6], vx, fmaf(w1[7], vy, fmaf(w1[8], vz, bb1[2])));
        h0 = prelu(h0, a1, oma1);
        h1 = prelu(h1, a1, oma1);
        h2 = prelu(h2, a1, oma1);
        float u0 = fmaf(w2[0], h0, fmaf(w2[1], h1, fmaf(w2[2], h2, bb2[0])));
        float u1 = fmaf(w2[3], h0, fmaf(w2[4], h1, fmaf(w2[5], h2, bb2[1])));
        float u2 = fmaf(w2[6], h0, fmaf(w2[7], h1, fmaf(w2[8], h2, bb2[2])));
        gx = prelu(u0, a2, oma2) + vx;
        gy = prelu(u1, a2, oma2) + vy;
        gz = prelu(u2, a2, oma2) + vz;
    };

    // lane ℓ owns global steps 32ℓ .. 32ℓ+31 (step 2047 of lane 63 is a dt=0 pad).
    // gyro float4 index base: (3 * 32 * lane)/4 = 24*lane; ts float4 base: 8*lane.
    const float4* gp = (const float4*)(gyro + (size_t)row * (CNT * 3));
    const float4* tp = (const float4*)(ts   + (size_t)row * CNT);
    const int gbase = 24 * lane;
    const int tbase = 8  * lane;

    Q q = {1.0f, 0.0f, 0.0f, 0.0f};
    float g0x, g0y, g0z;   // carried boundary g(t0 + 8m)

    #pragma unroll
    for (int m = 0; m < NMAC; ++m) {
        // ---- stream macro-chunk m: gyro floats [24m, 24m+28) = float4 6m..6m+6,
        //      ts floats [8m, 8m+12) = float4 2m..2m+2 (lane-relative)
        float4 Gv[7];
        #pragma unroll
        for (int k = 0; k < 7; ++k) {
            int gi = gbase + 6 * m + k;
            gi = gi > (CNT * 3 / 4 - 1) ? (CNT * 3 / 4 - 1) : gi;  // lane 63, m=3, k=6 only
            Gv[k] = gp[gi];
        }
        float4 Tv[3];
        #pragma unroll
        for (int k = 0; k < 3; ++k) {
            int ti = tbase + 2 * m + k;
            ti = ti > (CNT / 4 - 1) ? (CNT / 4 - 1) : ti;          // lane 63, m=3, k=2 only
            Tv[k] = tp[ti];
        }

        // SROA-safe unpack (constant indices only)
        float gg[28];
        #pragma unroll
        for (int k = 0; k < 7; ++k) {
            gg[4*k+0] = Gv[k].x; gg[4*k+1] = Gv[k].y;
            gg[4*k+2] = Gv[k].z; gg[4*k+3] = Gv[k].w;
        }
        float rtw[12];
        #pragma unroll
        for (int k = 0; k < 3; ++k) {
            rtw[4*k+0] = Tv[k].x; rtw[4*k+1] = Tv[k].y;
            rtw[4*k+2] = Tv[k].z; rtw[4*k+3] = Tv[k].w;
        }
        // pad step: lane 63's rtw[8] would be ts[2048]; force dt=0 (rtw[7]=ts[2047])
        if (m == NMAC - 1) rtw[8] = (lane == 63) ? rtw[7] : rtw[8];

        if (m == 0) gfv(gg[0], gg[1], gg[2], g0x, g0y, g0z);

        #pragma unroll
        for (int u = 0; u < MAC; ++u) {
            float g1x, g1y, g1z;
            gfv(gg[3*u+3], gg[3*u+4], gg[3*u+5], g1x, g1y, g1z);
            const float s = 0.25f * (rtw[u + 1] - rtw[u]);   // gm*dt*0.5
            q = qmul1(q, (g0x + g1x) * s, (g0y + g1y) * s, (g0z + g1z) * s);
            g0x = g1x; g0y = g1y; g0z = g1z;
        }
    }

    // normalize lane product (positive rescale; each qmul1 factor has norm >= 1)
    {
        const float n2  = fmaf(q.w, q.w, fmaf(q.x, q.x, fmaf(q.y, q.y, q.z * q.z)));
        const float inv = 1.0f / sqrtf(n2);
        q.w *= inv; q.x *= inv; q.y *= inv; q.z *= inv;
    }

    // ---- ordered 64-lane shuffle reduction: lane 0 gets P_0 ⊗ ... ⊗ P_63
    #pragma unroll
    for (int sft = 1; sft < 64; sft <<= 1) {
        Q o;
        o.w = __shfl_down(q.w, sft);
        o.x = __shfl_down(q.x, sft);
        o.y = __shfl_down(q.y, sft);
        o.z = __shfl_down(q.z, sft);
        q = qmul(q, o);
    }

    // ---- epilogue: whole row done within this wave — no LDS, no syncthreads
    if (lane == 0) {
        const float4 s0 = ((const float4*)(sq + (size_t)row * 4))[0];
        const Q q0 = {s0.x, s0.y, s0.z, s0.w};
        Q qf = qmul(q0, q);
        const float n   = sqrtf(fmaf(qf.w, qf.w, fmaf(qf.x, qf.x, fmaf(qf.y, qf.y, qf.z * qf.z))));
        const float inv = 1.0f / fmaxf(n, 1e-12f);
        float4 o;
        o.x = qf.w * inv; o.y = qf.x * inv; o.z = qf.y * inv; o.w = qf.z * inv;
        ((float4*)(out + (size_t)row * 4))[0] = o;
    }
}

extern "C" void kernel_launch(void* const* d_in, const int* in_sizes, int n_in,
                              void* d_out, int out_size, void* d_ws, size_t ws_size,
                              hipStream_t stream) {
    const float* ts   = (const float*)d_in[0];  // timestampns_set (B, CNT)
    const float* gyro = (const float*)d_in[1];  // gyro_set (B, CNT, 3)
    const float* sq   = (const float*)d_in[2];  // start_quat (B, 4)
    const float* W1   = (const float*)d_in[3];
    const float* b1   = (const float*)d_in[4];
    const float* a1   = (const float*)d_in[5];
    const float* W2   = (const float*)d_in[6];
    const float* b2   = (const float*)d_in[7];
    const float* a2   = (const float*)d_in[8];
    float* out = (float*)d_out;

    const int B = in_sizes[0] / CNT;  // 4096
    const int grid = (B + RPB - 1) / RPB;

    quat_scan_kernel<<<grid, TPB, 0, stream>>>(ts, gyro, sq, W1, b1, a1, W2, b2, a2, out, B);
}

// Round 6
// 200.293 us; speedup vs baseline: 1.0108x; 1.0108x over previous
//
#include <hip/hip_runtime.h>

#define CNT   2048
#define TPB   256
#define RPB   4        // rows per block = waves per block (one wave per row)

struct Q { float w, x, y, z; };

// full quaternion product: 16 fma-class ops, 3-deep chains
__device__ __forceinline__ Q qmul(const Q a, const Q b) {
    Q o;
    o.w = fmaf(a.w, b.w, fmaf(-a.x, b.x, fmaf(-a.y, b.y, -a.z * b.z)));
    o.x = fmaf(a.w, b.x, fmaf( a.x, b.w, fmaf( a.y, b.z, -a.z * b.y)));
    o.y = fmaf(a.w, b.y, fmaf(-a.x, b.z, fmaf( a.y, b.w,  a.z * b.x)));
    o.z = fmaf(a.w, b.z, fmaf( a.x, b.y, fmaf(-a.y, b.x,  a.z * b.w)));
    return o;
}

// qmul specialized for b.w == 1: 12 fma, 3-deep chains
__device__ __forceinline__ Q qmul1(const Q a, const float bx, const float by, const float bz) {
    Q o;
    o.w = fmaf(-a.x, bx, fmaf(-a.y, by, fmaf(-a.z, bz, a.w)));
    o.x = fmaf( a.w, bx, fmaf( a.y, bz, fmaf(-a.z, by, a.x)));
    o.y = fmaf( a.w, by, fmaf(-a.x, bz, fmaf( a.z, bx, a.y)));
    o.z = fmaf( a.w, bz, fmaf( a.x, by, fmaf(-a.y, bx, a.z)));
    return o;
}

// exact PReLU: a*x + (1-a)*relu(x) -> mul + max + fma
__device__ __forceinline__ float prelu(const float x, const float a, const float one_m_a) {
    return fmaf(one_m_a, fmaxf(x, 0.0f), a * x);
}

__global__ __launch_bounds__(TPB) void quat_scan_kernel(
    const float* __restrict__ ts,    // (B, CNT)
    const float* __restrict__ gyro,  // (B, CNT, 3)
    const float* __restrict__ sq,    // (B, 4)
    const float* __restrict__ W1, const float* __restrict__ b1, const float* __restrict__ a1p,
    const float* __restrict__ W2, const float* __restrict__ b2, const float* __restrict__ a2p,
    float* __restrict__ out,         // (B, 4)
    const int B)
{
    const int lane = threadIdx.x & 63;
    const int wid  = threadIdx.x >> 6;
    const int row  = blockIdx.x * RPB + wid;
    if (row >= B) return;            // wave-uniform exit

    // ---- small params: wave-uniform scalar loads -> SGPRs
    float w1[9], w2[9], bb1[3], bb2[3];
    #pragma unroll
    for (int i = 0; i < 9; ++i) { w1[i] = W1[i]; w2[i] = W2[i]; }
    #pragma unroll
    for (int i = 0; i < 3; ++i) { bb1[i] = b1[i]; bb2[i] = b2[i]; }
    const float a1 = a1p[0], a2 = a2p[0];
    const float oma1 = 1.0f - a1, oma2 = 1.0f - a2;

    // g(v) = prelu(W2 @ prelu(W1 @ v + b1, a1) + b2, a2) + v
    auto gfv = [&](const float vx, const float vy, const float vz,
                   float& gx, float& gy, float& gz) {
        float h0 = fmaf(w1[0], vx, fmaf(w1[1], vy, fmaf(w1[2], vz, bb1[0])));
        float h1 = fmaf(w1[3], vx, fmaf(w1[4], vy, fmaf(w1[5], vz, bb1[1])));
        float h2 = fmaf(w1[6], vx, fmaf(w1[7], vy, fmaf(w1[8], vz, bb1[2])));
        h0 = prelu(h0, a1, oma1);
        h1 = prelu(h1, a1, oma1);
        h2 = prelu(h2, a1, oma1);
        float u0 = fmaf(w2[0], h0, fmaf(w2[1], h1, fmaf(w2[2], h2, bb2[0])));
        float u1 = fmaf(w2[3], h0, fmaf(w2[4], h1, fmaf(w2[5], h2, bb2[1])));
        float u2 = fmaf(w2[6], h0, fmaf(w2[7], h1, fmaf(w2[8], h2, bb2[2])));
        gx = prelu(u0, a2, oma2) + vx;
        gy = prelu(u1, a2, oma2) + vy;
        gz = prelu(u2, a2, oma2) + vz;
    };

    // lane ℓ owns global steps 32ℓ..32ℓ+31 (step 2047 of lane 63 is the dt=0 pad).
    // Exact-fetch windows: per macro m, G = 6 float4 (floats 24m..24m+23),
    // T = 2 float4 (ts floats 8m..8m+7); step u=7 deferred into next buffer.
    const float4* gp = (const float4*)(gyro + (size_t)row * (CNT * 3));
    const float4* tp = (const float4*)(ts   + (size_t)row * CNT);
    const float*  tsr = ts + (size_t)row * CNT;
    const int gbase = 24 * lane;   // float4 units
    const int tbase = 8  * lane;   // float4 units

    Q q = {1.0f, 0.0f, 0.0f, 0.0f};
    float gpx, gpy, gpz;           // carried boundary g

// issue one macro-chunk's loads (literal indices; k unrolled)
#define LOADM(G, T, m) { \
    _Pragma("unroll") \
    for (int k = 0; k < 6; ++k) (G)[k] = gp[gbase + 6*(m) + k]; \
    (T)[0] = tp[tbase + 2*(m) + 0]; \
    (T)[1] = tp[tbase + 2*(m) + 1]; }

// one integration step: new g from (vx,vy,vz), dt from (tR - tL)
#define STEP(vx, vy, vz, tL, tR) { \
    float nx_, ny_, nz_; \
    gfv((vx), (vy), (vz), nx_, ny_, nz_); \
    const float s_ = 0.25f * ((tR) - (tL)); \
    q = qmul1(q, (gpx + nx_) * s_, (gpy + ny_) * s_, (gpz + nz_) * s_); \
    gpx = nx_; gpy = ny_; gpz = nz_; }

// steps u=0..6 of a macro, entirely within its own buffers (float j -> G[j/4][j%4])
#define MB(G, T) \
    STEP((G)[0].w, (G)[1].x, (G)[1].y, (T)[0].x, (T)[0].y) \
    STEP((G)[1].z, (G)[1].w, (G)[2].x, (T)[0].y, (T)[0].z) \
    STEP((G)[2].y, (G)[2].z, (G)[2].w, (T)[0].z, (T)[0].w) \
    STEP((G)[3].x, (G)[3].y, (G)[3].z, (T)[0].w, (T)[1].x) \
    STEP((G)[3].w, (G)[4].x, (G)[4].y, (T)[1].x, (T)[1].y) \
    STEP((G)[4].z, (G)[4].w, (G)[5].x, (T)[1].y, (T)[1].z) \
    STEP((G)[5].y, (G)[5].z, (G)[5].w, (T)[1].z, (T)[1].w)

// deferred step u=7: right g-sample and right ts live in the NEXT buffer
#define BD(Tc, Gn, Tn) \
    STEP((Gn)[0].x, (Gn)[0].y, (Gn)[0].z, (Tc)[1].w, (Tn)[0].x)

    float4 GA[6], TA[2], GB[6], TB[2];

    // prologue: buf A = macro 0; prefetch buf B = macro 1
    LOADM(GA, TA, 0)
    LOADM(GB, TB, 1)
    gfv(GA[0].x, GA[0].y, GA[0].z, gpx, gpy, gpz);   // g at first sample

    // m=0: compute A; boundary consumes B (already in flight); prefetch nothing yet
    MB(GA, TA)
    BD(TA, GB, TB)
    LOADM(GA, TA, 2)          // prefetch macro 2 while computing macro 1

    // m=1
    MB(GB, TB)
    BD(TB, GA, TA)
    LOADM(GB, TB, 3)          // prefetch macro 3 while computing macro 2

    // tail loads: first sample of the NEXT lane's region (clamped for lane 63)
    const int  gti = (gbase + 24 <= CNT * 3 / 4 - 1) ? (gbase + 24) : (CNT * 3 / 4 - 1);
    const int  tti = (32 * lane + 32 <= CNT - 1) ? (32 * lane + 32) : (CNT - 1);
    const float4 Gt = gp[gti];
    const float  Tt = tsr[tti];   // == ts[2047] for lane 63 -> pad step dt = 0

    // m=2
    MB(GA, TA)
    BD(TA, GB, TB)

    // m=3 (+ final boundary step; for lane 63 this is the dt=0 pad)
    MB(GB, TB)
    STEP(Gt.x, Gt.y, Gt.z, TB[1].w, Tt)

#undef LOADM
#undef STEP
#undef MB
#undef BD

    // normalize lane product (positive rescale; each qmul1 factor has norm >= 1)
    {
        const float n2  = fmaf(q.w, q.w, fmaf(q.x, q.x, fmaf(q.y, q.y, q.z * q.z)));
        const float inv = 1.0f / sqrtf(n2);
        q.w *= inv; q.x *= inv; q.y *= inv; q.z *= inv;
    }

    // ---- ordered 64-lane shuffle reduction: lane 0 gets P_0 ⊗ ... ⊗ P_63
    #pragma unroll
    for (int sft = 1; sft < 64; sft <<= 1) {
        Q o;
        o.w = __shfl_down(q.w, sft);
        o.x = __shfl_down(q.x, sft);
        o.y = __shfl_down(q.y, sft);
        o.z = __shfl_down(q.z, sft);
        q = qmul(q, o);
    }

    // ---- epilogue: whole row done within this wave — no LDS, no syncthreads
    if (lane == 0) {
        const float4 s0 = ((const float4*)(sq + (size_t)row * 4))[0];
        const Q q0 = {s0.x, s0.y, s0.z, s0.w};
        Q qf = qmul(q0, q);
        const float n   = sqrtf(fmaf(qf.w, qf.w, fmaf(qf.x, qf.x, fmaf(qf.y, qf.y, qf.z * qf.z))));
        const float inv = 1.0f / fmaxf(n, 1e-12f);
        float4 o;
        o.x = qf.w * inv; o.y = qf.x * inv; o.z = qf.y * inv; o.w = qf.z * inv;
        ((float4*)(out + (size_t)row * 4))[0] = o;
    }
}

extern "C" void kernel_launch(void* const* d_in, const int* in_sizes, int n_in,
                              void* d_out, int out_size, void* d_ws, size_t ws_size,
                              hipStream_t stream) {
    const float* ts   = (const float*)d_in[0];  // timestampns_set (B, CNT)
    const float* gyro = (const float*)d_in[1];  // gyro_set (B, CNT, 3)
    const float* sq   = (const float*)d_in[2];  // start_quat (B, 4)
    const float* W1   = (const float*)d_in[3];
    const float* b1   = (const float*)d_in[4];
    const float* a1   = (const float*)d_in[5];
    const float* W2   = (const float*)d_in[6];
    const float* b2   = (const float*)d_in[7];
    const float* a2   = (const float*)d_in[8];
    float* out = (float*)d_out;

    const int B = in_sizes[0] / CNT;  // 4096
    const int grid = (B + RPB - 1) / RPB;

    quat_scan_kernel<<<grid, TPB, 0, stream>>>(ts, gyro, sq, W1, b1, a1, W2, b2, a2, out, B);
}

// Round 7
// 192.429 us; speedup vs baseline: 1.0521x; 1.0409x over previous
//
#include <hip/hip_runtime.h>

#define CNT   2048
#define TPB   256
#define RPB   4        // rows per block = waves per block (one wave per row)

struct Q { float w, x, y, z; };

// full quaternion product: 16 fma-class ops, 3-deep chains
__device__ __forceinline__ Q qmul(const Q a, const Q b) {
    Q o;
    o.w = fmaf(a.w, b.w, fmaf(-a.x, b.x, fmaf(-a.y, b.y, -a.z * b.z)));
    o.x = fmaf(a.w, b.x, fmaf( a.x, b.w, fmaf( a.y, b.z, -a.z * b.y)));
    o.y = fmaf(a.w, b.y, fmaf(-a.x, b.z, fmaf( a.y, b.w,  a.z * b.x)));
    o.z = fmaf(a.w, b.z, fmaf( a.x, b.y, fmaf(-a.y, b.x,  a.z * b.w)));
    return o;
}

// qmul specialized for b.w == 1: 12 fma, 3-deep chains
__device__ __forceinline__ Q qmul1(const Q a, const float bx, const float by, const float bz) {
    Q o;
    o.w = fmaf(-a.x, bx, fmaf(-a.y, by, fmaf(-a.z, bz, a.w)));
    o.x = fmaf( a.w, bx, fmaf( a.y, bz, fmaf(-a.z, by, a.x)));
    o.y = fmaf( a.w, by, fmaf(-a.x, bz, fmaf( a.z, bx, a.y)));
    o.z = fmaf( a.w, bz, fmaf( a.x, by, fmaf(-a.y, bx, a.z)));
    return o;
}

// exact PReLU: a*x + (1-a)*relu(x) -> mul + max + fma
__device__ __forceinline__ float prelu(const float x, const float a, const float one_m_a) {
    return fmaf(one_m_a, fmaxf(x, 0.0f), a * x);
}

// grid supplies exactly 4 waves/SIMD (4096 waves / 1024 SIMDs) -> tell the
// register allocator the truth: 4 waves/EU => 128-VGPR budget, so the
// double-buffer can live in registers instead of being re-sunk to uses.
__global__ __launch_bounds__(TPB, 4) void quat_scan_kernel(
    const float* __restrict__ ts,    // (B, CNT)
    const float* __restrict__ gyro,  // (B, CNT, 3)
    const float* __restrict__ sq,    // (B, 4)
    const float* __restrict__ W1, const float* __restrict__ b1, const float* __restrict__ a1p,
    const float* __restrict__ W2, const float* __restrict__ b2, const float* __restrict__ a2p,
    float* __restrict__ out,         // (B, 4)
    const int B)
{
    const int lane = threadIdx.x & 63;
    const int wid  = threadIdx.x >> 6;
    const int row  = blockIdx.x * RPB + wid;
    if (row >= B) return;            // wave-uniform exit (never taken at B=4096)

    // ---- small params: wave-uniform scalar loads -> SGPRs
    float w1[9], w2[9], bb1[3], bb2[3];
    #pragma unroll
    for (int i = 0; i < 9; ++i) { w1[i] = W1[i]; w2[i] = W2[i]; }
    #pragma unroll
    for (int i = 0; i < 3; ++i) { bb1[i] = b1[i]; bb2[i] = b2[i]; }
    const float a1 = a1p[0], a2 = a2p[0];
    const float oma1 = 1.0f - a1, oma2 = 1.0f - a2;

    // g(v) = prelu(W2 @ prelu(W1 @ v + b1, a1) + b2, a2) + v
    auto gfv = [&](const float vx, const float vy, const float vz,
                   float& gx, float& gy, float& gz) {
        float h0 = fmaf(w1[0], vx, fmaf(w1[1], vy, fmaf(w1[2], vz, bb1[0])));
        float h1 = fmaf(w1[3], vx, fmaf(w1[4], vy, fmaf(w1[5], vz, bb1[1])));
        float h2 = fmaf(w1[6], vx, fmaf(w1[7], vy, fmaf(w1[8], vz, bb1[2])));
        h0 = prelu(h0, a1, oma1);
        h1 = prelu(h1, a1, oma1);
        h2 = prelu(h2, a1, oma1);
        float u0 = fmaf(w2[0], h0, fmaf(w2[1], h1, fmaf(w2[2], h2, bb2[0])));
        float u1 = fmaf(w2[3], h0, fmaf(w2[4], h1, fmaf(w2[5], h2, bb2[1])));
        float u2 = fmaf(w2[6], h0, fmaf(w2[7], h1, fmaf(w2[8], h2, bb2[2])));
        gx = prelu(u0, a2, oma2) + vx;
        gy = prelu(u1, a2, oma2) + vy;
        gz = prelu(u2, a2, oma2) + vz;
    };

    // lane ℓ owns global steps 32ℓ..32ℓ+31 (step 2047 of lane 63 is the dt=0 pad).
    // Exact-fetch windows: per macro m, G = 6 float4 (floats 24m..24m+23),
    // T = 2 float4 (ts floats 8m..8m+7); step u=7 deferred into next buffer.
    const float4* gp = (const float4*)(gyro + (size_t)row * (CNT * 3));
    const float4* tp = (const float4*)(ts   + (size_t)row * CNT);
    const float*  tsr = ts + (size_t)row * CNT;
    const int gbase = 24 * lane;   // float4 units
    const int tbase = 8  * lane;   // float4 units

    Q q = {1.0f, 0.0f, 0.0f, 0.0f};
    float gpx, gpy, gpz;           // carried boundary g

// issue one macro-chunk's loads (literal indices; k unrolled)
#define LOADM(G, T, m) { \
    _Pragma("unroll") \
    for (int k = 0; k < 6; ++k) (G)[k] = gp[gbase + 6*(m) + k]; \
    (T)[0] = tp[tbase + 2*(m) + 0]; \
    (T)[1] = tp[tbase + 2*(m) + 1]; }

// scheduling fence: NOTHING crosses (IR side-effect + MIR region boundary).
// Pins each load cluster ABOVE the following compute so the backend cannot
// re-sink loads to their uses (which is what produced VGPR=32 / zero overlap).
#define SFENCE __builtin_amdgcn_sched_barrier(0)

// one integration step: new g from (vx,vy,vz), dt from (tR - tL)
#define STEP(vx, vy, vz, tL, tR) { \
    float nx_, ny_, nz_; \
    gfv((vx), (vy), (vz), nx_, ny_, nz_); \
    const float s_ = 0.25f * ((tR) - (tL)); \
    q = qmul1(q, (gpx + nx_) * s_, (gpy + ny_) * s_, (gpz + nz_) * s_); \
    gpx = nx_; gpy = ny_; gpz = nz_; }

// steps u=0..6 of a macro, entirely within its own buffers (float j -> G[j/4][j%4])
#define MB(G, T) \
    STEP((G)[0].w, (G)[1].x, (G)[1].y, (T)[0].x, (T)[0].y) \
    STEP((G)[1].z, (G)[1].w, (G)[2].x, (T)[0].y, (T)[0].z) \
    STEP((G)[2].y, (G)[2].z, (G)[2].w, (T)[0].z, (T)[0].w) \
    STEP((G)[3].x, (G)[3].y, (G)[3].z, (T)[0].w, (T)[1].x) \
    STEP((G)[3].w, (G)[4].x, (G)[4].y, (T)[1].x, (T)[1].y) \
    STEP((G)[4].z, (G)[4].w, (G)[5].x, (T)[1].y, (T)[1].z) \
    STEP((G)[5].y, (G)[5].z, (G)[5].w, (T)[1].z, (T)[1].w)

// deferred step u=7: right g-sample and right ts live in the NEXT buffer
#define BD(Tc, Gn, Tn) \
    STEP((Gn)[0].x, (Gn)[0].y, (Gn)[0].z, (Tc)[1].w, (Tn)[0].x)

    float4 GA[6], TA[2], GB[6], TB[2];

    // prologue: buf A = macro 0; prefetch buf B = macro 1; fence pins both clusters
    LOADM(GA, TA, 0)
    LOADM(GB, TB, 1)
    SFENCE;
    gfv(GA[0].x, GA[0].y, GA[0].z, gpx, gpy, gpz);   // g at first sample

    // macro 0 compute; then issue macro-2 loads and fence them above macro-1 compute
    MB(GA, TA)
    BD(TA, GB, TB)
    LOADM(GA, TA, 2)
    SFENCE;

    // macro 1 compute; issue macro-3 loads + tail loads, fence above macro-2 compute
    MB(GB, TB)
    BD(TB, GA, TA)
    LOADM(GB, TB, 3)
    // tail: first sample of the NEXT lane's region (clamped for lane 63)
    const int  gti = (gbase + 24 <= CNT * 3 / 4 - 1) ? (gbase + 24) : (CNT * 3 / 4 - 1);
    const int  tti = (32 * lane + 32 <= CNT - 1) ? (32 * lane + 32) : (CNT - 1);
    const float4 Gt = gp[gti];
    const float  Tt = tsr[tti];   // == ts[2047] for lane 63 -> pad step dt = 0
    SFENCE;

    // macro 2
    MB(GA, TA)
    BD(TA, GB, TB)

    // macro 3 (+ final boundary step; for lane 63 this is the dt=0 pad)
    MB(GB, TB)
    STEP(Gt.x, Gt.y, Gt.z, TB[1].w, Tt)

#undef LOADM
#undef STEP
#undef MB
#undef BD
#undef SFENCE

    // normalize lane product (positive rescale; each qmul1 factor has norm >= 1)
    {
        const float n2  = fmaf(q.w, q.w, fmaf(q.x, q.x, fmaf(q.y, q.y, q.z * q.z)));
        const float inv = 1.0f / sqrtf(n2);
        q.w *= inv; q.x *= inv; q.y *= inv; q.z *= inv;
    }

    // ---- ordered 64-lane shuffle reduction: lane 0 gets P_0 ⊗ ... ⊗ P_63
    #pragma unroll
    for (int sft = 1; sft < 64; sft <<= 1) {
        Q o;
        o.w = __shfl_down(q.w, sft);
        o.x = __shfl_down(q.x, sft);
        o.y = __shfl_down(q.y, sft);
        o.z = __shfl_down(q.z, sft);
        q = qmul(q, o);
    }

    // ---- epilogue: whole row done within this wave — no LDS, no syncthreads
    if (lane == 0) {
        const float4 s0 = ((const float4*)(sq + (size_t)row * 4))[0];
        const Q q0 = {s0.x, s0.y, s0.z, s0.w};
        Q qf = qmul(q0, q);
        const float n   = sqrtf(fmaf(qf.w, qf.w, fmaf(qf.x, qf.x, fmaf(qf.y, qf.y, qf.z * qf.z))));
        const float inv = 1.0f / fmaxf(n, 1e-12f);
        float4 o;
        o.x = qf.w * inv; o.y = qf.x * inv; o.z = qf.y * inv; o.w = qf.z * inv;
        ((float4*)(out + (size_t)row * 4))[0] = o;
    }
}

extern "C" void kernel_launch(void* const* d_in, const int* in_sizes, int n_in,
                              void* d_out, int out_size, void* d_ws, size_t ws_size,
                              hipStream_t stream) {
    const float* ts   = (const float*)d_in[0];  // timestampns_set (B, CNT)
    const float* gyro = (const float*)d_in[1];  // gyro_set (B, CNT, 3)
    const float* sq   = (const float*)d_in[2];  // start_quat (B, 4)
    const float* W1   = (const float*)d_in[3];
    const float* b1   = (const float*)d_in[4];
    const float* a1   = (const float*)d_in[5];
    const float* W2   = (const float*)d_in[6];
    const float* b2   = (const float*)d_in[7];
    const float* a2   = (const float*)d_in[8];
    float* out = (float*)d_out;

    const int B = in_sizes[0] / CNT;  // 4096
    const int grid = (B + RPB - 1) / RPB;

    quat_scan_kernel<<<grid, TPB, 0, stream>>>(ts, gyro, sq, W1, b1, a1, W2, b2, a2, out, B);
}